// Round 14
// baseline (206.905 us; speedup 1.0000x reference)
//
#include <hip/hip_runtime.h>
#include <math.h>

// B=8, T=1024, E=1024, H=16 heads x 64 dim. All GEMMs: M=8192, N=K=1024.
// Pipeline (4 dispatches):
//   prep: rope table + cast xq,xkv->bf16 + transpose-cast 4 weights (one launch)
//   fused QKV GEMM (2-phase 128x128, launch_bounds (256,4) — (256,5) squeezed
//     VGPR 64->48 and spilled, r12), RoPE via table in epilogue
//   flash attention v3: swapped-QK^T 32x32x16 MFMA, fixed-max exp2 softmax,
//     hb-fastest remap, T14 dbuf staging (loads before compute, writes after,
//     ONE barrier/tile), LDS-unioned epilogue. Never raise launch_bounds min
//     (r11: (256,8) squeezed VGPR 64->32, 1.1 GB spill).
//   out = Oatt @ Wo^T (2-phase 128x128, f32 out)

typedef __attribute__((ext_vector_type(8))) short bf16x8;
typedef __attribute__((ext_vector_type(4))) float f32x4;
typedef __attribute__((ext_vector_type(16))) float f32x16;

#define LOG2E 1.44269504f
#define QSCALE (0.125f * LOG2E)

__device__ __forceinline__ ushort f2bf(float f) {
    union { float f; uint32_t u; } v; v.f = f;
    uint32_t r = (v.u + 0x7FFF + ((v.u >> 16) & 1)) >> 16;
    return (ushort)r;
}
__device__ __forceinline__ uint cvt_pk_bf16(float a, float b) {
    uint r;
    asm("v_cvt_pk_bf16_f32 %0, %1, %2" : "=v"(r) : "v"(a), "v"(b));
    return r;
}
__device__ __forceinline__ float bf2f(ushort u) {
    union { uint32_t u; float f; } v; v.u = ((uint32_t)u) << 16;
    return v.f;
}

__device__ __forceinline__ void gload16(const ushort* g, ushort* l) {
    __builtin_amdgcn_global_load_lds(
        (const __attribute__((address_space(1))) unsigned int*)g,
        (__attribute__((address_space(3))) unsigned int*)l, 16, 0, 0);
}

// ---------------------------------------------------------------------------
// prep: flat grid 12416 x 256.
//   bid in [0,8192):      cast f32->bf16, 8 elems/thread (xq then xkv)
//   bid in [8192,12288):  transpose+cast weights (4 x 32x32-tile grids)
//   bid in [12288,12416): rope table tbl[t*32+i] = (cos,sin)(t * 10000^(-i/32))
// ---------------------------------------------------------------------------
__global__ void prep(const float* __restrict__ xq,  ushort* __restrict__ Aq,
                     const float* __restrict__ xkv, ushort* __restrict__ Akv,
                     const float* __restrict__ wq,  ushort* __restrict__ WqT,
                     const float* __restrict__ wk,  ushort* __restrict__ WkT,
                     const float* __restrict__ wv,  ushort* __restrict__ WvT,
                     const float* __restrict__ wo,  ushort* __restrict__ WoT,
                     float2* __restrict__ tbl)
{
    __shared__ float t[32][33];
    const int bid = blockIdx.x;
    const int tid = threadIdx.x;

    if (bid < 8192) {
        const float* X = (bid < 4096) ? xq : xkv;
        ushort* Y = (bid < 4096) ? Aq : Akv;
        int i = (bid & 4095) * 256 + tid;
        float4 a = ((const float4*)X)[2 * i];
        float4 b = ((const float4*)X)[2 * i + 1];
        union { float4 f; ushort u[8]; } o;
        o.u[0] = f2bf(a.x); o.u[1] = f2bf(a.y); o.u[2] = f2bf(a.z); o.u[3] = f2bf(a.w);
        o.u[4] = f2bf(b.x); o.u[5] = f2bf(b.y); o.u[6] = f2bf(b.z); o.u[7] = f2bf(b.w);
        ((float4*)Y)[i] = o.f;
    } else if (bid < 12288) {
        int j = bid - 8192;
        int z = j >> 10, rem = j & 1023;
        const float* W = (z == 0) ? wq : (z == 1) ? wk : (z == 2) ? wv : wo;
        ushort* Wt = (z == 0) ? WqT : (z == 1) ? WkT : (z == 2) ? WvT : WoT;
        int bx = (rem & 31) * 32, by = (rem >> 5) * 32;
        int tx = tid & 31, ty = tid >> 5;   // 32 x 8
#pragma unroll
        for (int e = 0; e < 32; e += 8)
            t[ty + e][tx] = W[(size_t)(by + ty + e) * 1024 + bx + tx];
        __syncthreads();
#pragma unroll
        for (int e = 0; e < 32; e += 8)
            Wt[(size_t)(bx + ty + e) * 1024 + by + tx] = f2bf(t[tx][ty + e]);
    } else {
        int idx = (bid - 12288) * 256 + tid;   // 0..32767
        int tt = idx >> 5, i = idx & 31;
        float inv_freq = exp2f(-(float)i * (13.28771238f / 32.0f));
        float s, c;
        sincosf((float)tt * inv_freq, &s, &c);
        tbl[idx] = make_float2(c, s);
    }
}

// ---------------------------------------------------------------------------
// Fused QKV GEMM: for mat in {0,1,2}: Out_mat = A_mat @ Wt_mat^T.
// 128x128 tile, BK=32, 2-phase double-buffered; grid (64, 24),
// mat = by>>3, col-tile = by&7. RoPE (table-driven) folded into epilogue
// for mat 0/1 (Q additionally scaled by 0.125*log2e for exp2 softmax).
// ---------------------------------------------------------------------------
__global__ __launch_bounds__(256, 4)
void gemm_qkv(const ushort* __restrict__ Aq, const ushort* __restrict__ Akv,
              const ushort* __restrict__ Wt, ushort* __restrict__ Out,
              const float2* __restrict__ tbl)
{
    const int K = 1024, N = 1024;
    __shared__ ushort As[2][128 * 32];
    __shared__ ushort Bs[2][128 * 32];
    const int tid = threadIdx.x;
    const int w = tid >> 6, l = tid & 63;
    const int mat = blockIdx.y >> 3;
    const int row0 = blockIdx.x * 128, col0 = (blockIdx.y & 7) * 128;
    const int wr = (w >> 1) * 64, wc = (w & 1) * 64;

    const ushort* A = mat ? Akv : Aq;
    const ushort* Bt = Wt + (size_t)mat * (1024 * 1024);
    ushort* C = Out + (size_t)mat * 8388608;

    f32x4 acc[4][4];
#pragma unroll
    for (int i = 0; i < 4; ++i)
#pragma unroll
        for (int j = 0; j < 4; ++j) acc[i][j] = (f32x4)0.f;

    const ushort* Ag = A + (size_t)(row0 + w * 32 + (l >> 2)) * K + (l & 3) * 8;
    const ushort* Bg = Bt + (size_t)(col0 + w * 32 + (l >> 2)) * K + (l & 3) * 8;

    const int arow = (wr + (l & 15)) * 32;
    const int brow = (wc + (l & 15)) * 32;
    const int koff = (l >> 4) * 8;

    auto STAGE = [&](int buf, int kt) {
        ushort* Asw = &As[buf][w * 1024];
        ushort* Bsw = &Bs[buf][w * 1024];
        gload16(Ag + kt, Asw);
        gload16(Ag + 16 * K + kt, Asw + 512);
        gload16(Bg + kt, Bsw);
        gload16(Bg + 16 * K + kt, Bsw + 512);
    };
    auto COMPUTE = [&](int buf) {
        bf16x8 af[4], bfr[4];
#pragma unroll
        for (int fm = 0; fm < 4; ++fm)
            af[fm] = *(const bf16x8*)&As[buf][arow + fm * 512 + koff];
#pragma unroll
        for (int fn = 0; fn < 4; ++fn)
            bfr[fn] = *(const bf16x8*)&Bs[buf][brow + fn * 512 + koff];
#pragma unroll
        for (int fm = 0; fm < 4; ++fm)
#pragma unroll
            for (int fn = 0; fn < 4; ++fn)
                acc[fm][fn] = __builtin_amdgcn_mfma_f32_16x16x32_bf16(
                    af[fm], bfr[fn], acc[fm][fn], 0, 0, 0);
    };

    STAGE(0, 0);
    asm volatile("s_waitcnt vmcnt(0)" ::: "memory");
    __builtin_amdgcn_s_barrier();
    int cur = 0;
    for (int kt = 32; kt < K; kt += 32) {
        STAGE(cur ^ 1, kt);
        COMPUTE(cur);
        asm volatile("s_waitcnt vmcnt(0)" ::: "memory");
        __builtin_amdgcn_s_barrier();
        cur ^= 1;
    }
    COMPUTE(cur);

    const int crow = (l >> 4) * 4;
    const int ccol = l & 15;

    // RoPE epilogue for Q (mat 0, * 0.125*log2e) and K (mat 1), via table
    if (mat < 2) {
        const float scale = (mat == 0) ? QSCALE : 1.0f;
        const int odd = ccol & 1;
        int ipair[4];
#pragma unroll
        for (int fn = 0; fn < 4; ++fn)
            ipair[fn] = (fn * 16 + ccol) >> 1;       // head-dim pair idx 0..31
#pragma unroll
        for (int fm = 0; fm < 4; ++fm)
#pragma unroll
            for (int r = 0; r < 4; ++r) {
                int t = (row0 + wr + fm * 16 + crow + r) & 1023;
                const float2* tb = tbl + (t << 5);
#pragma unroll
                for (int fn = 0; fn < 4; ++fn) {
                    float x = acc[fm][fn][r];
                    float partner = __shfl_xor(x, 1, 64);
                    float2 cs = tb[ipair[fn]];
                    float o = odd ? fmaf(partner, cs.y, x * cs.x)
                                  : fmaf(-partner, cs.y, x * cs.x);
                    acc[fm][fn][r] = o * scale;
                }
            }
    }

#pragma unroll
    for (int fm = 0; fm < 4; ++fm)
#pragma unroll
        for (int fn = 0; fn < 4; ++fn)
#pragma unroll
            for (int r = 0; r < 4; ++r) {
                size_t row = row0 + wr + fm * 16 + crow + r;
                size_t col = col0 + wc + fn * 16 + ccol;
                C[row * N + col] = f2bf(acc[fm][fn][r]);
            }
}

// ---------------------------------------------------------------------------
// Final GEMM: C[M][N] = A[M][K] @ Bt[N][K]^T, f32 out (2-phase, 128x128).
// ---------------------------------------------------------------------------
__global__ __launch_bounds__(256, 2)
void gemm_out(const ushort* __restrict__ A, const ushort* __restrict__ Bt,
              float* __restrict__ C, int M, int N, int K)
{
    __shared__ ushort As[2][128 * 32];
    __shared__ ushort Bs[2][128 * 32];
    const int tid = threadIdx.x;
    const int w = tid >> 6, l = tid & 63;
    const int row0 = blockIdx.x * 128, col0 = blockIdx.y * 128;
    const int wr = (w >> 1) * 64, wc = (w & 1) * 64;

    f32x4 acc[4][4];
#pragma unroll
    for (int i = 0; i < 4; ++i)
#pragma unroll
        for (int j = 0; j < 4; ++j) acc[i][j] = (f32x4)0.f;

    const ushort* Ag = A + (size_t)(row0 + w * 32 + (l >> 2)) * K + (l & 3) * 8;
    const ushort* Bg = Bt + (size_t)(col0 + w * 32 + (l >> 2)) * K + (l & 3) * 8;

    const int arow = (wr + (l & 15)) * 32;
    const int brow = (wc + (l & 15)) * 32;
    const int koff = (l >> 4) * 8;

    auto STAGE = [&](int buf, int kt) {
        ushort* Asw = &As[buf][w * 1024];
        ushort* Bsw = &Bs[buf][w * 1024];
        gload16(Ag + kt, Asw);
        gload16(Ag + 16 * K + kt, Asw + 512);
        gload16(Bg + kt, Bsw);
        gload16(Bg + 16 * K + kt, Bsw + 512);
    };
    auto COMPUTE = [&](int buf) {
        bf16x8 af[4], bfr[4];
#pragma unroll
        for (int fm = 0; fm < 4; ++fm)
            af[fm] = *(const bf16x8*)&As[buf][arow + fm * 512 + koff];
#pragma unroll
        for (int fn = 0; fn < 4; ++fn)
            bfr[fn] = *(const bf16x8*)&Bs[buf][brow + fn * 512 + koff];
#pragma unroll
        for (int fm = 0; fm < 4; ++fm)
#pragma unroll
            for (int fn = 0; fn < 4; ++fn)
                acc[fm][fn] = __builtin_amdgcn_mfma_f32_16x16x32_bf16(
                    af[fm], bfr[fn], acc[fm][fn], 0, 0, 0);
    };

    STAGE(0, 0);
    asm volatile("s_waitcnt vmcnt(0)" ::: "memory");
    __builtin_amdgcn_s_barrier();
    int cur = 0;
    for (int kt = 32; kt < K; kt += 32) {
        STAGE(cur ^ 1, kt);
        COMPUTE(cur);
        asm volatile("s_waitcnt vmcnt(0)" ::: "memory");
        __builtin_amdgcn_s_barrier();
        cur ^= 1;
    }
    COMPUTE(cur);

    const int crow = (l >> 4) * 4;
    const int ccol = l & 15;
#pragma unroll
    for (int fm = 0; fm < 4; ++fm)
#pragma unroll
        for (int fn = 0; fn < 4; ++fn)
#pragma unroll
            for (int r = 0; r < 4; ++r) {
                size_t row = row0 + wr + fm * 16 + crow + r;
                size_t col = col0 + wc + fn * 16 + ccol;
                C[row * N + col] = acc[fm][fn][r];
            }
}

// ---------------------------------------------------------------------------
// Flash attention v3: swapped QK^T, 32x32x16 MFMA, fixed-max exp2 softmax.
// Q pre-scaled by 0.125*log2e. Block = 4 waves x 32 q = 128 q of one (b,h).
// 1D grid 1024, hb-fastest: bid = qt*128 + (h*8+b).
// T14 dbuf: LDS 2 x 17.4 KB; per tile: issue t+1 loads -> compute(t) ->
// ds_write t+1 to buf^1 -> ONE barrier. Epilogue reuses shm[0] per-wave.
// ---------------------------------------------------------------------------
__global__ __launch_bounds__(256, 4)
void attn_bf16_v3(const ushort* __restrict__ Q, const ushort* __restrict__ K,
                  const ushort* __restrict__ V, ushort* __restrict__ O)
{
    __shared__ uint shm[2][4352];     // per buf: Ksu [0,2176) ; Vtu [2176,4352)

    const int tid = threadIdx.x;
    const int w = tid >> 6, l = tid & 63;
    const int lo = l & 31, hi = l >> 5;
    const int bid = blockIdx.x;
    const int qt = bid >> 7;
    const int hb = bid & 127;
    const int h = hb >> 3, b = hb & 7;
    const int colh = h * 64;

    const size_t qrow = (size_t)(b * 1024 + qt * 128 + w * 32 + lo);
    bf16x8 qb[4];
#pragma unroll
    for (int kc = 0; kc < 4; ++kc)
        qb[kc] = *(const bf16x8*)&Q[qrow * 1024 + colh + kc * 16 + hi * 8];

    f32x16 acc[2];
#pragma unroll
    for (int i = 0; i < 2; ++i) acc[i] = (f32x16)0.f;
    float lsum = 0.f;

    const size_t kvbase = (size_t)b * 1024 * 1024 + colh;  // + key*1024 + d

    const int skey = tid >> 3, sc = tid & 7;  // K staging
    const int kp = tid & 31, vg = tid >> 5;   // V staging

    const ushort* Kg = &K[kvbase + (size_t)skey * 1024 + sc * 8];
    const ushort* Vg = &V[kvbase + (size_t)(2 * kp) * 1024 + vg * 8];

    // prologue: stage tile 0 -> buf 0
    {
        uint4 k0 = *(const uint4*)Kg;
        uint4 k1 = *(const uint4*)(Kg + 32 * 1024);
        uint4 v0 = *(const uint4*)Vg;
        uint4 v1 = *(const uint4*)(Vg + 1024);
        uint* Ksu = shm[0];
        uint* Vtu = shm[0] + 2176;
        *(uint2*)&Ksu[skey * 34 + sc * 4]            = make_uint2(k0.x, k0.y);
        *(uint2*)&Ksu[skey * 34 + sc * 4 + 2]        = make_uint2(k0.z, k0.w);
        *(uint2*)&Ksu[(skey + 32) * 34 + sc * 4]     = make_uint2(k1.x, k1.y);
        *(uint2*)&Ksu[(skey + 32) * 34 + sc * 4 + 2] = make_uint2(k1.z, k1.w);
        const ushort* pa = (const ushort*)&v0;
        const ushort* pb = (const ushort*)&v1;
#pragma unroll
        for (int e = 0; e < 8; ++e)
            Vtu[(vg * 8 + e) * 34 + kp] = (uint)pa[e] | ((uint)pb[e] << 16);
    }
    __syncthreads();

#pragma unroll 1
    for (int kt = 0; kt < 16; ++kt) {
        const uint* Ksu = shm[kt & 1];
        const uint* Vtu = shm[kt & 1] + 2176;
        const bool more = (kt < 15);

        // issue next tile's global loads (latency hides under compute)
        uint4 nk0, nk1, nv0, nv1;
        if (more) {
            const ushort* Kn = Kg + (size_t)(kt + 1) * 64 * 1024;
            const ushort* Vn = Vg + (size_t)(kt + 1) * 64 * 1024;
            nk0 = *(const uint4*)Kn;
            nk1 = *(const uint4*)(Kn + 32 * 1024);
            nv0 = *(const uint4*)Vn;
            nv1 = *(const uint4*)(Vn + 1024);
        }

        // S^T = K Q^T per 32-key tile; fixed-max exp2 softmax; pack P^T
        uint pw[16];
#pragma unroll
        for (int mt = 0; mt < 2; ++mt) {
            f32x16 s = (f32x16)0.f;
            const int rbase = (mt * 32 + lo) * 34 + hi * 4;
#pragma unroll
            for (int kc = 0; kc < 4; ++kc) {
                union { uint2 d[2]; bf16x8 v; } ak;
                ak.d[0] = *(const uint2*)&Ksu[rbase + kc * 8];
                ak.d[1] = *(const uint2*)&Ksu[rbase + kc * 8 + 2];
                s = __builtin_amdgcn_mfma_f32_32x32x16_bf16(ak.v, qb[kc], s, 0, 0, 0);
            }
            float p[16];
#pragma unroll
            for (int r = 0; r < 16; ++r) {
                p[r] = exp2f(s[r]);
                lsum += p[r];
            }
#pragma unroll
            for (int rp = 0; rp < 8; ++rp)
                pw[mt * 8 + rp] = cvt_pk_bf16(p[2 * rp], p[2 * rp + 1]);
        }

        // build P^T B-fragments in-register via half-wave exchange
        bf16x8 pf[4];
#pragma unroll
        for (int mt = 0; mt < 2; ++mt) {
            uint* W = &pw[mt * 8];
            uint e0 = (uint)__shfl_xor((int)(hi ? W[0] : W[2]), 32);
            uint e1 = (uint)__shfl_xor((int)(hi ? W[1] : W[3]), 32);
            uint e2 = (uint)__shfl_xor((int)(hi ? W[4] : W[6]), 32);
            uint e3 = (uint)__shfl_xor((int)(hi ? W[5] : W[7]), 32);
            union { uint u[4]; bf16x8 v; } f0, f1;
            if (hi == 0) {
                f0.u[0] = W[0]; f0.u[1] = W[1]; f0.u[2] = e0; f0.u[3] = e1;
                f1.u[0] = W[4]; f1.u[1] = W[5]; f1.u[2] = e2; f1.u[3] = e3;
            } else {
                f0.u[0] = e0; f0.u[1] = e1; f0.u[2] = W[2]; f0.u[3] = W[3];
                f1.u[0] = e2; f1.u[1] = e3; f1.u[2] = W[6]; f1.u[3] = W[7];
            }
            pf[mt * 2 + 0] = f0.v;
            pf[mt * 2 + 1] = f1.v;
        }

        // O^T += V^T P^T
#pragma unroll
        for (int dmt = 0; dmt < 2; ++dmt) {
            const int rbase = (dmt * 32 + lo) * 34 + hi * 4;
#pragma unroll
            for (int kcg = 0; kcg < 4; ++kcg) {
                union { uint2 d[2]; bf16x8 v; } vk;
                vk.d[0] = *(const uint2*)&Vtu[rbase + kcg * 8];
                vk.d[1] = *(const uint2*)&Vtu[rbase + kcg * 8 + 2];
                acc[dmt] = __builtin_amdgcn_mfma_f32_32x32x16_bf16(vk.v, pf[kcg], acc[dmt], 0, 0, 0);
            }
        }

        // write staged regs -> buf^1 (nobody reads it this tile)
        if (more) {
            uint* Kd = shm[(kt & 1) ^ 1];
            uint* Vd = shm[(kt & 1) ^ 1] + 2176;
            *(uint2*)&Kd[skey * 34 + sc * 4]            = make_uint2(nk0.x, nk0.y);
            *(uint2*)&Kd[skey * 34 + sc * 4 + 2]        = make_uint2(nk0.z, nk0.w);
            *(uint2*)&Kd[(skey + 32) * 34 + sc * 4]     = make_uint2(nk1.x, nk1.y);
            *(uint2*)&Kd[(skey + 32) * 34 + sc * 4 + 2] = make_uint2(nk1.z, nk1.w);
            const ushort* pa = (const ushort*)&nv0;
            const ushort* pb = (const ushort*)&nv1;
#pragma unroll
            for (int e = 0; e < 8; ++e)
                Vd[(vg * 8 + e) * 34 + kp] = (uint)pa[e] | ((uint)pb[e] << 16);
        }
        __syncthreads();   // buf^1 staged AND all waves done reading buf
    }

    float tot = lsum + __shfl_xor(lsum, 32);
    float inv = 1.0f / tot;

    // epilogue O^T -> O via per-wave LDS regions in shm[0] (loop barrier
    // guarantees all K/V reads complete; regions are wave-private anyway)
    uint* Osw = shm[0] + w * 1056;     // 32 rows x 33 u32 per wave
#pragma unroll
    for (int dmt = 0; dmt < 2; ++dmt)
#pragma unroll
        for (int rp = 0; rp < 8; ++rp) {
            float a0 = acc[dmt][2 * rp] * inv;
            float a1 = acc[dmt][2 * rp + 1] * inv;
            Osw[lo * 33 + dmt * 16 + (rp & 1) + 4 * (rp >> 1) + 2 * hi] =
                cvt_pk_bf16(a0, a1);
        }
    __builtin_amdgcn_s_waitcnt(0);     // lgkm drain before same-wave readback
#pragma unroll
    for (int u = 0; u < 4; ++u) {
        int slot = l + u * 64;
        int qr = slot >> 3, c = slot & 7;
        float4 val = *(const float4*)&Osw[qr * 33 + c * 4];
        *(float4*)&O[(size_t)(b * 1024 + qt * 128 + w * 32 + qr) * 1024 + colh + c * 8] = val;
    }
}

// ---------------------------------------------------------------------------
extern "C" void kernel_launch(void* const* d_in, const int* in_sizes, int n_in,
                              void* d_out, int out_size, void* d_ws, size_t ws_size,
                              hipStream_t stream)
{
    const float* xq  = (const float*)d_in[0];
    const float* xkv = (const float*)d_in[1];
    const float* wq  = (const float*)d_in[2];
    const float* wk  = (const float*)d_in[3];
    const float* wv  = (const float*)d_in[4];
    const float* wo  = (const float*)d_in[5];
    float* out = (float*)d_out;

    const int M = 8192, N = 1024, Kd = 1024;
    ushort* Aq  = (ushort*)d_ws;            // 8M bf16
    ushort* Akv = Aq  + 8388608;
    ushort* WqT = Akv + 8388608;            // 1M each; WqT/WkT/WvT contiguous
    ushort* WkT = WqT + 1048576;
    ushort* WvT = WkT + 1048576;
    ushort* WoT = WvT + 1048576;
    ushort* Qb  = WoT + 1048576;            // 8M each; Qb/Kb/Vb contiguous
    ushort* Kb  = Qb  + 8388608;
    ushort* Vb  = Kb  + 8388608;
    ushort* Ob  = Vb  + 8388608;
    float2* Tbl = (float2*)(Ob + 8388608);  // 32768 float2 = 256 KB

    prep<<<12416, 256, 0, stream>>>(xq, Aq, xkv, Akv, wq, WqT, wk, WkT,
                                    wv, WvT, wo, WoT, Tbl);

    gemm_qkv<<<dim3(64, 24), 256, 0, stream>>>(Aq, Akv, WqT, Qb, Tbl);

    attn_bf16_v3<<<1024, 256, 0, stream>>>(Qb, Kb, Vb, Ob);

    gemm_out<<<dim3(64, 8), 256, 0, stream>>>(Ob, WoT, out, M, N, Kd);
}

// Round 15
// 178.735 us; speedup vs baseline: 1.1576x; 1.1576x over previous
//
#include <hip/hip_runtime.h>
#include <math.h>

// B=8, T=1024, E=1024, H=16 heads x 64 dim. All GEMMs: M=8192, N=K=1024.
// Pipeline (4 dispatches) — best verified configuration (r13, 178.4 us):
//   prep: rope table + cast xq,xkv->bf16 + transpose-cast 4 weights (one launch)
//   fused QKV GEMM (2-phase 128x128, launch_bounds (256,4)), RoPE in epilogue
//   flash attention, swapped-QK^T 32x32x16 MFMA, fixed-max exp2 softmax,
//     hb-fastest remap, LDS-unioned epilogue buffer (17.4 KB)
//   out = Oatt @ Wo^T (2-phase 128x128, f32 out)
// REFUTED on this workload (do not retry): deep-pipeline GEMM (r8 2-wave,
// r9 256^2 8-phase — K=1024 too short, grid/LDS kill occupancy); reg-staged
// K/V prefetch in attn (r4, r14 — spills); launch_bounds min-wave raises
// (r11 attn (256,8): VGPR 32 + 1.1GB spill; r12 qkv (256,5): VGPR 48 + spill).

typedef __attribute__((ext_vector_type(8))) short bf16x8;
typedef __attribute__((ext_vector_type(4))) float f32x4;
typedef __attribute__((ext_vector_type(16))) float f32x16;

#define LOG2E 1.44269504f
#define QSCALE (0.125f * LOG2E)

__device__ __forceinline__ ushort f2bf(float f) {
    union { float f; uint32_t u; } v; v.f = f;
    uint32_t r = (v.u + 0x7FFF + ((v.u >> 16) & 1)) >> 16;
    return (ushort)r;
}
__device__ __forceinline__ uint cvt_pk_bf16(float a, float b) {
    uint r;
    asm("v_cvt_pk_bf16_f32 %0, %1, %2" : "=v"(r) : "v"(a), "v"(b));
    return r;
}
__device__ __forceinline__ float bf2f(ushort u) {
    union { uint32_t u; float f; } v; v.u = ((uint32_t)u) << 16;
    return v.f;
}

__device__ __forceinline__ void gload16(const ushort* g, ushort* l) {
    __builtin_amdgcn_global_load_lds(
        (const __attribute__((address_space(1))) unsigned int*)g,
        (__attribute__((address_space(3))) unsigned int*)l, 16, 0, 0);
}

// ---------------------------------------------------------------------------
// prep: flat grid 12416 x 256.
//   bid in [0,8192):      cast f32->bf16, 8 elems/thread (xq then xkv)
//   bid in [8192,12288):  transpose+cast weights (4 x 32x32-tile grids)
//   bid in [12288,12416): rope table tbl[t*32+i] = (cos,sin)(t * 10000^(-i/32))
// ---------------------------------------------------------------------------
__global__ void prep(const float* __restrict__ xq,  ushort* __restrict__ Aq,
                     const float* __restrict__ xkv, ushort* __restrict__ Akv,
                     const float* __restrict__ wq,  ushort* __restrict__ WqT,
                     const float* __restrict__ wk,  ushort* __restrict__ WkT,
                     const float* __restrict__ wv,  ushort* __restrict__ WvT,
                     const float* __restrict__ wo,  ushort* __restrict__ WoT,
                     float2* __restrict__ tbl)
{
    __shared__ float t[32][33];
    const int bid = blockIdx.x;
    const int tid = threadIdx.x;

    if (bid < 8192) {
        const float* X = (bid < 4096) ? xq : xkv;
        ushort* Y = (bid < 4096) ? Aq : Akv;
        int i = (bid & 4095) * 256 + tid;
        float4 a = ((const float4*)X)[2 * i];
        float4 b = ((const float4*)X)[2 * i + 1];
        union { float4 f; ushort u[8]; } o;
        o.u[0] = f2bf(a.x); o.u[1] = f2bf(a.y); o.u[2] = f2bf(a.z); o.u[3] = f2bf(a.w);
        o.u[4] = f2bf(b.x); o.u[5] = f2bf(b.y); o.u[6] = f2bf(b.z); o.u[7] = f2bf(b.w);
        ((float4*)Y)[i] = o.f;
    } else if (bid < 12288) {
        int j = bid - 8192;
        int z = j >> 10, rem = j & 1023;
        const float* W = (z == 0) ? wq : (z == 1) ? wk : (z == 2) ? wv : wo;
        ushort* Wt = (z == 0) ? WqT : (z == 1) ? WkT : (z == 2) ? WvT : WoT;
        int bx = (rem & 31) * 32, by = (rem >> 5) * 32;
        int tx = tid & 31, ty = tid >> 5;   // 32 x 8
#pragma unroll
        for (int e = 0; e < 32; e += 8)
            t[ty + e][tx] = W[(size_t)(by + ty + e) * 1024 + bx + tx];
        __syncthreads();
#pragma unroll
        for (int e = 0; e < 32; e += 8)
            Wt[(size_t)(bx + ty + e) * 1024 + by + tx] = f2bf(t[tx][ty + e]);
    } else {
        int idx = (bid - 12288) * 256 + tid;   // 0..32767
        int tt = idx >> 5, i = idx & 31;
        float inv_freq = exp2f(-(float)i * (13.28771238f / 32.0f));
        float s, c;
        sincosf((float)tt * inv_freq, &s, &c);
        tbl[idx] = make_float2(c, s);
    }
}

// ---------------------------------------------------------------------------
// Fused QKV GEMM: for mat in {0,1,2}: Out_mat = A_mat @ Wt_mat^T.
// 128x128 tile, BK=32, 2-phase double-buffered; grid (64, 24),
// mat = by>>3, col-tile = by&7. RoPE (table-driven) folded into epilogue
// for mat 0/1 (Q additionally scaled by 0.125*log2e for exp2 softmax).
// ---------------------------------------------------------------------------
__global__ __launch_bounds__(256, 4)
void gemm_qkv(const ushort* __restrict__ Aq, const ushort* __restrict__ Akv,
              const ushort* __restrict__ Wt, ushort* __restrict__ Out,
              const float2* __restrict__ tbl)
{
    const int K = 1024, N = 1024;
    __shared__ ushort As[2][128 * 32];
    __shared__ ushort Bs[2][128 * 32];
    const int tid = threadIdx.x;
    const int w = tid >> 6, l = tid & 63;
    const int mat = blockIdx.y >> 3;
    const int row0 = blockIdx.x * 128, col0 = (blockIdx.y & 7) * 128;
    const int wr = (w >> 1) * 64, wc = (w & 1) * 64;

    const ushort* A = mat ? Akv : Aq;
    const ushort* Bt = Wt + (size_t)mat * (1024 * 1024);
    ushort* C = Out + (size_t)mat * 8388608;

    f32x4 acc[4][4];
#pragma unroll
    for (int i = 0; i < 4; ++i)
#pragma unroll
        for (int j = 0; j < 4; ++j) acc[i][j] = (f32x4)0.f;

    const ushort* Ag = A + (size_t)(row0 + w * 32 + (l >> 2)) * K + (l & 3) * 8;
    const ushort* Bg = Bt + (size_t)(col0 + w * 32 + (l >> 2)) * K + (l & 3) * 8;

    const int arow = (wr + (l & 15)) * 32;
    const int brow = (wc + (l & 15)) * 32;
    const int koff = (l >> 4) * 8;

    auto STAGE = [&](int buf, int kt) {
        ushort* Asw = &As[buf][w * 1024];
        ushort* Bsw = &Bs[buf][w * 1024];
        gload16(Ag + kt, Asw);
        gload16(Ag + 16 * K + kt, Asw + 512);
        gload16(Bg + kt, Bsw);
        gload16(Bg + 16 * K + kt, Bsw + 512);
    };
    auto COMPUTE = [&](int buf) {
        bf16x8 af[4], bfr[4];
#pragma unroll
        for (int fm = 0; fm < 4; ++fm)
            af[fm] = *(const bf16x8*)&As[buf][arow + fm * 512 + koff];
#pragma unroll
        for (int fn = 0; fn < 4; ++fn)
            bfr[fn] = *(const bf16x8*)&Bs[buf][brow + fn * 512 + koff];
#pragma unroll
        for (int fm = 0; fm < 4; ++fm)
#pragma unroll
            for (int fn = 0; fn < 4; ++fn)
                acc[fm][fn] = __builtin_amdgcn_mfma_f32_16x16x32_bf16(
                    af[fm], bfr[fn], acc[fm][fn], 0, 0, 0);
    };

    STAGE(0, 0);
    asm volatile("s_waitcnt vmcnt(0)" ::: "memory");
    __builtin_amdgcn_s_barrier();
    int cur = 0;
    for (int kt = 32; kt < K; kt += 32) {
        STAGE(cur ^ 1, kt);
        COMPUTE(cur);
        asm volatile("s_waitcnt vmcnt(0)" ::: "memory");
        __builtin_amdgcn_s_barrier();
        cur ^= 1;
    }
    COMPUTE(cur);

    const int crow = (l >> 4) * 4;
    const int ccol = l & 15;

    // RoPE epilogue for Q (mat 0, * 0.125*log2e) and K (mat 1), via table
    if (mat < 2) {
        const float scale = (mat == 0) ? QSCALE : 1.0f;
        const int odd = ccol & 1;
        int ipair[4];
#pragma unroll
        for (int fn = 0; fn < 4; ++fn)
            ipair[fn] = (fn * 16 + ccol) >> 1;       // head-dim pair idx 0..31
#pragma unroll
        for (int fm = 0; fm < 4; ++fm)
#pragma unroll
            for (int r = 0; r < 4; ++r) {
                int t = (row0 + wr + fm * 16 + crow + r) & 1023;
                const float2* tb = tbl + (t << 5);
#pragma unroll
                for (int fn = 0; fn < 4; ++fn) {
                    float x = acc[fm][fn][r];
                    float partner = __shfl_xor(x, 1, 64);
                    float2 cs = tb[ipair[fn]];
                    float o = odd ? fmaf(partner, cs.y, x * cs.x)
                                  : fmaf(-partner, cs.y, x * cs.x);
                    acc[fm][fn][r] = o * scale;
                }
            }
    }

#pragma unroll
    for (int fm = 0; fm < 4; ++fm)
#pragma unroll
        for (int fn = 0; fn < 4; ++fn)
#pragma unroll
            for (int r = 0; r < 4; ++r) {
                size_t row = row0 + wr + fm * 16 + crow + r;
                size_t col = col0 + wc + fn * 16 + ccol;
                C[row * N + col] = f2bf(acc[fm][fn][r]);
            }
}

// ---------------------------------------------------------------------------
// Final GEMM: C[M][N] = A[M][K] @ Bt[N][K]^T, f32 out (2-phase, 128x128).
// ---------------------------------------------------------------------------
__global__ __launch_bounds__(256, 2)
void gemm_out(const ushort* __restrict__ A, const ushort* __restrict__ Bt,
              float* __restrict__ C, int M, int N, int K)
{
    __shared__ ushort As[2][128 * 32];
    __shared__ ushort Bs[2][128 * 32];
    const int tid = threadIdx.x;
    const int w = tid >> 6, l = tid & 63;
    const int row0 = blockIdx.x * 128, col0 = blockIdx.y * 128;
    const int wr = (w >> 1) * 64, wc = (w & 1) * 64;

    f32x4 acc[4][4];
#pragma unroll
    for (int i = 0; i < 4; ++i)
#pragma unroll
        for (int j = 0; j < 4; ++j) acc[i][j] = (f32x4)0.f;

    const ushort* Ag = A + (size_t)(row0 + w * 32 + (l >> 2)) * K + (l & 3) * 8;
    const ushort* Bg = Bt + (size_t)(col0 + w * 32 + (l >> 2)) * K + (l & 3) * 8;

    const int arow = (wr + (l & 15)) * 32;
    const int brow = (wc + (l & 15)) * 32;
    const int koff = (l >> 4) * 8;

    auto STAGE = [&](int buf, int kt) {
        ushort* Asw = &As[buf][w * 1024];
        ushort* Bsw = &Bs[buf][w * 1024];
        gload16(Ag + kt, Asw);
        gload16(Ag + 16 * K + kt, Asw + 512);
        gload16(Bg + kt, Bsw);
        gload16(Bg + 16 * K + kt, Bsw + 512);
    };
    auto COMPUTE = [&](int buf) {
        bf16x8 af[4], bfr[4];
#pragma unroll
        for (int fm = 0; fm < 4; ++fm)
            af[fm] = *(const bf16x8*)&As[buf][arow + fm * 512 + koff];
#pragma unroll
        for (int fn = 0; fn < 4; ++fn)
            bfr[fn] = *(const bf16x8*)&Bs[buf][brow + fn * 512 + koff];
#pragma unroll
        for (int fm = 0; fm < 4; ++fm)
#pragma unroll
            for (int fn = 0; fn < 4; ++fn)
                acc[fm][fn] = __builtin_amdgcn_mfma_f32_16x16x32_bf16(
                    af[fm], bfr[fn], acc[fm][fn], 0, 0, 0);
    };

    STAGE(0, 0);
    asm volatile("s_waitcnt vmcnt(0)" ::: "memory");
    __builtin_amdgcn_s_barrier();
    int cur = 0;
    for (int kt = 32; kt < K; kt += 32) {
        STAGE(cur ^ 1, kt);
        COMPUTE(cur);
        asm volatile("s_waitcnt vmcnt(0)" ::: "memory");
        __builtin_amdgcn_s_barrier();
        cur ^= 1;
    }
    COMPUTE(cur);

    const int crow = (l >> 4) * 4;
    const int ccol = l & 15;
#pragma unroll
    for (int fm = 0; fm < 4; ++fm)
#pragma unroll
        for (int fn = 0; fn < 4; ++fn)
#pragma unroll
            for (int r = 0; r < 4; ++r) {
                size_t row = row0 + wr + fm * 16 + crow + r;
                size_t col = col0 + wc + fn * 16 + ccol;
                C[row * N + col] = acc[fm][fn][r];
            }
}

// ---------------------------------------------------------------------------
// Flash attention: swapped QK^T, 32x32x16 MFMA, fixed-max exp2 softmax.
// Q pre-scaled by 0.125*log2e. Block = 4 waves x 32 q = 128 q of one (b,h).
// 1D grid 1024, hb-fastest: bid = qt*128 + (h*8+b).
// LDS: Ksu/Vtu (17.4 KB) reused for the O^T->O epilogue buffer (union).
// launch_bounds min kept at 4: VGPR stays 64 -> HW gives 8 blocks/CU anyway.
// ---------------------------------------------------------------------------
__global__ __launch_bounds__(256, 4)
void attn_bf16_v2(const ushort* __restrict__ Q, const ushort* __restrict__ K,
                  const ushort* __restrict__ V, ushort* __restrict__ O)
{
    __shared__ uint shm[4352];        // Ksu [0,2176) ; Vtu [2176,4352)
    uint* Ksu = shm;                  // K tile u32 pairs, row stride 34
    uint* Vtu = shm + 2176;           // V^T tile: row d, cols key-pairs

    const int tid = threadIdx.x;
    const int w = tid >> 6, l = tid & 63;
    const int lo = l & 31, hi = l >> 5;
    const int bid = blockIdx.x;
    const int qt = bid >> 7;
    const int hb = bid & 127;
    const int h = hb >> 3, b = hb & 7;
    const int colh = h * 64;

    const size_t qrow = (size_t)(b * 1024 + qt * 128 + w * 32 + lo);
    bf16x8 qb[4];
#pragma unroll
    for (int kc = 0; kc < 4; ++kc)
        qb[kc] = *(const bf16x8*)&Q[qrow * 1024 + colh + kc * 16 + hi * 8];

    f32x16 acc[2];
#pragma unroll
    for (int i = 0; i < 2; ++i) acc[i] = (f32x16)0.f;
    float lsum = 0.f;

    const size_t kvbase = (size_t)b * 1024 * 1024 + colh;  // + key*1024 + d

    const int skey = tid >> 3, sc = tid & 7;  // K staging
    const int kp = tid & 31, vg = tid >> 5;   // V staging

    for (int kt = 0; kt < 16; ++kt) {
        __syncthreads();
#pragma unroll
        for (int u = 0; u < 2; ++u) {
            int key = skey + u * 32;
            uint4 kv = *(const uint4*)&K[kvbase + (size_t)(kt * 64 + key) * 1024 + sc * 8];
            *(uint2*)&Ksu[key * 34 + sc * 4] = make_uint2(kv.x, kv.y);
            *(uint2*)&Ksu[key * 34 + sc * 4 + 2] = make_uint2(kv.z, kv.w);
        }
        {
            uint4 va = *(const uint4*)&V[kvbase + (size_t)(kt * 64 + 2 * kp) * 1024 + vg * 8];
            uint4 vb = *(const uint4*)&V[kvbase + (size_t)(kt * 64 + 2 * kp + 1) * 1024 + vg * 8];
            const ushort* pa = (const ushort*)&va;
            const ushort* pb = (const ushort*)&vb;
#pragma unroll
            for (int e = 0; e < 8; ++e)
                Vtu[(vg * 8 + e) * 34 + kp] = (uint)pa[e] | ((uint)pb[e] << 16);
        }
        __syncthreads();

        uint pw[16];
#pragma unroll
        for (int mt = 0; mt < 2; ++mt) {
            f32x16 s = (f32x16)0.f;
            const int rbase = (mt * 32 + lo) * 34 + hi * 4;
#pragma unroll
            for (int kc = 0; kc < 4; ++kc) {
                union { uint2 d[2]; bf16x8 v; } ak;
                ak.d[0] = *(const uint2*)&Ksu[rbase + kc * 8];
                ak.d[1] = *(const uint2*)&Ksu[rbase + kc * 8 + 2];
                s = __builtin_amdgcn_mfma_f32_32x32x16_bf16(ak.v, qb[kc], s, 0, 0, 0);
            }
            float p[16];
#pragma unroll
            for (int r = 0; r < 16; ++r) {
                p[r] = exp2f(s[r]);
                lsum += p[r];
            }
#pragma unroll
            for (int rp = 0; rp < 8; ++rp)
                pw[mt * 8 + rp] = cvt_pk_bf16(p[2 * rp], p[2 * rp + 1]);
        }

        bf16x8 pf[4];
#pragma unroll
        for (int mt = 0; mt < 2; ++mt) {
            uint* W = &pw[mt * 8];
            uint e0 = (uint)__shfl_xor((int)(hi ? W[0] : W[2]), 32);
            uint e1 = (uint)__shfl_xor((int)(hi ? W[1] : W[3]), 32);
            uint e2 = (uint)__shfl_xor((int)(hi ? W[4] : W[6]), 32);
            uint e3 = (uint)__shfl_xor((int)(hi ? W[5] : W[7]), 32);
            union { uint u[4]; bf16x8 v; } f0, f1;
            if (hi == 0) {
                f0.u[0] = W[0]; f0.u[1] = W[1]; f0.u[2] = e0; f0.u[3] = e1;
                f1.u[0] = W[4]; f1.u[1] = W[5]; f1.u[2] = e2; f1.u[3] = e3;
            } else {
                f0.u[0] = e0; f0.u[1] = e1; f0.u[2] = W[2]; f0.u[3] = W[3];
                f1.u[0] = e2; f1.u[1] = e3; f1.u[2] = W[6]; f1.u[3] = W[7];
            }
            pf[mt * 2 + 0] = f0.v;
            pf[mt * 2 + 1] = f1.v;
        }

#pragma unroll
        for (int dmt = 0; dmt < 2; ++dmt) {
            const int rbase = (dmt * 32 + lo) * 34 + hi * 4;
#pragma unroll
            for (int kcg = 0; kcg < 4; ++kcg) {
                union { uint2 d[2]; bf16x8 v; } vk;
                vk.d[0] = *(const uint2*)&Vtu[rbase + kcg * 8];
                vk.d[1] = *(const uint2*)&Vtu[rbase + kcg * 8 + 2];
                acc[dmt] = __builtin_amdgcn_mfma_f32_32x32x16_bf16(vk.v, pf[kcg], acc[dmt], 0, 0, 0);
            }
        }
    }

    float tot = lsum + __shfl_xor(lsum, 32);
    float inv = 1.0f / tot;

    // epilogue O^T -> O via LDS union (Ksu/Vtu space is dead after the loop)
    __syncthreads();                   // all waves done reading K/V tiles
    uint* Osw = shm + w * 1056;        // 32 rows x 33 u32 per wave
#pragma unroll
    for (int dmt = 0; dmt < 2; ++dmt)
#pragma unroll
        for (int rp = 0; rp < 8; ++rp) {
            float a0 = acc[dmt][2 * rp] * inv;
            float a1 = acc[dmt][2 * rp + 1] * inv;
            Osw[lo * 33 + dmt * 16 + (rp & 1) + 4 * (rp >> 1) + 2 * hi] =
                cvt_pk_bf16(a0, a1);
        }
    __builtin_amdgcn_s_waitcnt(0);     // lgkm drain before same-wave readback
#pragma unroll
    for (int u = 0; u < 4; ++u) {
        int slot = l + u * 64;
        int qr = slot >> 3, c = slot & 7;
        float4 val = *(const float4*)&Osw[qr * 33 + c * 4];
        *(float4*)&O[(size_t)(b * 1024 + qt * 128 + w * 32 + qr) * 1024 + colh + c * 8] = val;
    }
}

// ---------------------------------------------------------------------------
extern "C" void kernel_launch(void* const* d_in, const int* in_sizes, int n_in,
                              void* d_out, int out_size, void* d_ws, size_t ws_size,
                              hipStream_t stream)
{
    const float* xq  = (const float*)d_in[0];
    const float* xkv = (const float*)d_in[1];
    const float* wq  = (const float*)d_in[2];
    const float* wk  = (const float*)d_in[3];
    const float* wv  = (const float*)d_in[4];
    const float* wo  = (const float*)d_in[5];
    float* out = (float*)d_out;

    const int M = 8192, N = 1024, Kd = 1024;
    ushort* Aq  = (ushort*)d_ws;            // 8M bf16
    ushort* Akv = Aq  + 8388608;
    ushort* WqT = Akv + 8388608;            // 1M each; WqT/WkT/WvT contiguous
    ushort* WkT = WqT + 1048576;
    ushort* WvT = WkT + 1048576;
    ushort* WoT = WvT + 1048576;
    ushort* Qb  = WoT + 1048576;            // 8M each; Qb/Kb/Vb contiguous
    ushort* Kb  = Qb  + 8388608;
    ushort* Vb  = Kb  + 8388608;
    ushort* Ob  = Vb  + 8388608;
    float2* Tbl = (float2*)(Ob + 8388608);  // 32768 float2 = 256 KB

    prep<<<12416, 256, 0, stream>>>(xq, Aq, xkv, Akv, wq, WqT, wk, WkT,
                                    wv, WvT, wo, WoT, Tbl);

    gemm_qkv<<<dim3(64, 24), 256, 0, stream>>>(Aq, Akv, WqT, Qb, Tbl);

    attn_bf16_v2<<<1024, 256, 0, stream>>>(Qb, Kb, Vb, Ob);

    gemm_out<<<dim3(64, 8), 256, 0, stream>>>(Ob, WoT, out, M, N, Kd);
}

// Round 16
// 177.189 us; speedup vs baseline: 1.1677x; 1.0087x over previous
//
#include <hip/hip_runtime.h>
#include <math.h>

// B=8, T=1024, E=1024, H=16 heads x 64 dim. All GEMMs: M=8192, N=K=1024.
// Pipeline (4 dispatches) — r13/r15 base (178.4/178.7 us) + T5 setprio in attn:
//   prep: rope table + cast xq,xkv->bf16 + transpose-cast 4 weights (one launch)
//   fused QKV GEMM (2-phase 128x128, launch_bounds (256,4)), RoPE in epilogue
//   flash attention, swapped-QK^T 32x32x16 MFMA, fixed-max exp2 softmax,
//     hb-fastest remap, LDS-unioned epilogue (17.4 KB), setprio on MFMA clusters
//   out = Oatt @ Wo^T (2-phase 128x128, f32 out)
// REFUTED on this workload (do not retry): deep-pipeline GEMM (r8 2-wave,
// r9 256^2 8-phase — K=1024 too short); reg-staged K/V prefetch in attn
// (r4, r14 — spills); launch_bounds min-wave raises (r11, r12 — VGPR squeeze).

typedef __attribute__((ext_vector_type(8))) short bf16x8;
typedef __attribute__((ext_vector_type(4))) float f32x4;
typedef __attribute__((ext_vector_type(16))) float f32x16;

#define LOG2E 1.44269504f
#define QSCALE (0.125f * LOG2E)

__device__ __forceinline__ ushort f2bf(float f) {
    union { float f; uint32_t u; } v; v.f = f;
    uint32_t r = (v.u + 0x7FFF + ((v.u >> 16) & 1)) >> 16;
    return (ushort)r;
}
__device__ __forceinline__ uint cvt_pk_bf16(float a, float b) {
    uint r;
    asm("v_cvt_pk_bf16_f32 %0, %1, %2" : "=v"(r) : "v"(a), "v"(b));
    return r;
}
__device__ __forceinline__ float bf2f(ushort u) {
    union { uint32_t u; float f; } v; v.u = ((uint32_t)u) << 16;
    return v.f;
}

__device__ __forceinline__ void gload16(const ushort* g, ushort* l) {
    __builtin_amdgcn_global_load_lds(
        (const __attribute__((address_space(1))) unsigned int*)g,
        (__attribute__((address_space(3))) unsigned int*)l, 16, 0, 0);
}

// ---------------------------------------------------------------------------
// prep: flat grid 12416 x 256.
// ---------------------------------------------------------------------------
__global__ void prep(const float* __restrict__ xq,  ushort* __restrict__ Aq,
                     const float* __restrict__ xkv, ushort* __restrict__ Akv,
                     const float* __restrict__ wq,  ushort* __restrict__ WqT,
                     const float* __restrict__ wk,  ushort* __restrict__ WkT,
                     const float* __restrict__ wv,  ushort* __restrict__ WvT,
                     const float* __restrict__ wo,  ushort* __restrict__ WoT,
                     float2* __restrict__ tbl)
{
    __shared__ float t[32][33];
    const int bid = blockIdx.x;
    const int tid = threadIdx.x;

    if (bid < 8192) {
        const float* X = (bid < 4096) ? xq : xkv;
        ushort* Y = (bid < 4096) ? Aq : Akv;
        int i = (bid & 4095) * 256 + tid;
        float4 a = ((const float4*)X)[2 * i];
        float4 b = ((const float4*)X)[2 * i + 1];
        union { float4 f; ushort u[8]; } o;
        o.u[0] = f2bf(a.x); o.u[1] = f2bf(a.y); o.u[2] = f2bf(a.z); o.u[3] = f2bf(a.w);
        o.u[4] = f2bf(b.x); o.u[5] = f2bf(b.y); o.u[6] = f2bf(b.z); o.u[7] = f2bf(b.w);
        ((float4*)Y)[i] = o.f;
    } else if (bid < 12288) {
        int j = bid - 8192;
        int z = j >> 10, rem = j & 1023;
        const float* W = (z == 0) ? wq : (z == 1) ? wk : (z == 2) ? wv : wo;
        ushort* Wt = (z == 0) ? WqT : (z == 1) ? WkT : (z == 2) ? WvT : WoT;
        int bx = (rem & 31) * 32, by = (rem >> 5) * 32;
        int tx = tid & 31, ty = tid >> 5;   // 32 x 8
#pragma unroll
        for (int e = 0; e < 32; e += 8)
            t[ty + e][tx] = W[(size_t)(by + ty + e) * 1024 + bx + tx];
        __syncthreads();
#pragma unroll
        for (int e = 0; e < 32; e += 8)
            Wt[(size_t)(bx + ty + e) * 1024 + by + tx] = f2bf(t[tx][ty + e]);
    } else {
        int idx = (bid - 12288) * 256 + tid;   // 0..32767
        int tt = idx >> 5, i = idx & 31;
        float inv_freq = exp2f(-(float)i * (13.28771238f / 32.0f));
        float s, c;
        sincosf((float)tt * inv_freq, &s, &c);
        tbl[idx] = make_float2(c, s);
    }
}

// ---------------------------------------------------------------------------
// Fused QKV GEMM: 128x128 tile, BK=32, 2-phase; grid (64, 24).
// ---------------------------------------------------------------------------
__global__ __launch_bounds__(256, 4)
void gemm_qkv(const ushort* __restrict__ Aq, const ushort* __restrict__ Akv,
              const ushort* __restrict__ Wt, ushort* __restrict__ Out,
              const float2* __restrict__ tbl)
{
    const int K = 1024, N = 1024;
    __shared__ ushort As[2][128 * 32];
    __shared__ ushort Bs[2][128 * 32];
    const int tid = threadIdx.x;
    const int w = tid >> 6, l = tid & 63;
    const int mat = blockIdx.y >> 3;
    const int row0 = blockIdx.x * 128, col0 = (blockIdx.y & 7) * 128;
    const int wr = (w >> 1) * 64, wc = (w & 1) * 64;

    const ushort* A = mat ? Akv : Aq;
    const ushort* Bt = Wt + (size_t)mat * (1024 * 1024);
    ushort* C = Out + (size_t)mat * 8388608;

    f32x4 acc[4][4];
#pragma unroll
    for (int i = 0; i < 4; ++i)
#pragma unroll
        for (int j = 0; j < 4; ++j) acc[i][j] = (f32x4)0.f;

    const ushort* Ag = A + (size_t)(row0 + w * 32 + (l >> 2)) * K + (l & 3) * 8;
    const ushort* Bg = Bt + (size_t)(col0 + w * 32 + (l >> 2)) * K + (l & 3) * 8;

    const int arow = (wr + (l & 15)) * 32;
    const int brow = (wc + (l & 15)) * 32;
    const int koff = (l >> 4) * 8;

    auto STAGE = [&](int buf, int kt) {
        ushort* Asw = &As[buf][w * 1024];
        ushort* Bsw = &Bs[buf][w * 1024];
        gload16(Ag + kt, Asw);
        gload16(Ag + 16 * K + kt, Asw + 512);
        gload16(Bg + kt, Bsw);
        gload16(Bg + 16 * K + kt, Bsw + 512);
    };
    auto COMPUTE = [&](int buf) {
        bf16x8 af[4], bfr[4];
#pragma unroll
        for (int fm = 0; fm < 4; ++fm)
            af[fm] = *(const bf16x8*)&As[buf][arow + fm * 512 + koff];
#pragma unroll
        for (int fn = 0; fn < 4; ++fn)
            bfr[fn] = *(const bf16x8*)&Bs[buf][brow + fn * 512 + koff];
#pragma unroll
        for (int fm = 0; fm < 4; ++fm)
#pragma unroll
            for (int fn = 0; fn < 4; ++fn)
                acc[fm][fn] = __builtin_amdgcn_mfma_f32_16x16x32_bf16(
                    af[fm], bfr[fn], acc[fm][fn], 0, 0, 0);
    };

    STAGE(0, 0);
    asm volatile("s_waitcnt vmcnt(0)" ::: "memory");
    __builtin_amdgcn_s_barrier();
    int cur = 0;
    for (int kt = 32; kt < K; kt += 32) {
        STAGE(cur ^ 1, kt);
        COMPUTE(cur);
        asm volatile("s_waitcnt vmcnt(0)" ::: "memory");
        __builtin_amdgcn_s_barrier();
        cur ^= 1;
    }
    COMPUTE(cur);

    const int crow = (l >> 4) * 4;
    const int ccol = l & 15;

    // RoPE epilogue for Q (mat 0, * 0.125*log2e) and K (mat 1), via table
    if (mat < 2) {
        const float scale = (mat == 0) ? QSCALE : 1.0f;
        const int odd = ccol & 1;
        int ipair[4];
#pragma unroll
        for (int fn = 0; fn < 4; ++fn)
            ipair[fn] = (fn * 16 + ccol) >> 1;       // head-dim pair idx 0..31
#pragma unroll
        for (int fm = 0; fm < 4; ++fm)
#pragma unroll
            for (int r = 0; r < 4; ++r) {
                int t = (row0 + wr + fm * 16 + crow + r) & 1023;
                const float2* tb = tbl + (t << 5);
#pragma unroll
                for (int fn = 0; fn < 4; ++fn) {
                    float x = acc[fm][fn][r];
                    float partner = __shfl_xor(x, 1, 64);
                    float2 cs = tb[ipair[fn]];
                    float o = odd ? fmaf(partner, cs.y, x * cs.x)
                                  : fmaf(-partner, cs.y, x * cs.x);
                    acc[fm][fn][r] = o * scale;
                }
            }
    }

#pragma unroll
    for (int fm = 0; fm < 4; ++fm)
#pragma unroll
        for (int fn = 0; fn < 4; ++fn)
#pragma unroll
            for (int r = 0; r < 4; ++r) {
                size_t row = row0 + wr + fm * 16 + crow + r;
                size_t col = col0 + wc + fn * 16 + ccol;
                C[row * N + col] = f2bf(acc[fm][fn][r]);
            }
}

// ---------------------------------------------------------------------------
// Final GEMM: C[M][N] = A[M][K] @ Bt[N][K]^T, f32 out (2-phase, 128x128).
// ---------------------------------------------------------------------------
__global__ __launch_bounds__(256, 2)
void gemm_out(const ushort* __restrict__ A, const ushort* __restrict__ Bt,
              float* __restrict__ C, int M, int N, int K)
{
    __shared__ ushort As[2][128 * 32];
    __shared__ ushort Bs[2][128 * 32];
    const int tid = threadIdx.x;
    const int w = tid >> 6, l = tid & 63;
    const int row0 = blockIdx.x * 128, col0 = blockIdx.y * 128;
    const int wr = (w >> 1) * 64, wc = (w & 1) * 64;

    f32x4 acc[4][4];
#pragma unroll
    for (int i = 0; i < 4; ++i)
#pragma unroll
        for (int j = 0; j < 4; ++j) acc[i][j] = (f32x4)0.f;

    const ushort* Ag = A + (size_t)(row0 + w * 32 + (l >> 2)) * K + (l & 3) * 8;
    const ushort* Bg = Bt + (size_t)(col0 + w * 32 + (l >> 2)) * K + (l & 3) * 8;

    const int arow = (wr + (l & 15)) * 32;
    const int brow = (wc + (l & 15)) * 32;
    const int koff = (l >> 4) * 8;

    auto STAGE = [&](int buf, int kt) {
        ushort* Asw = &As[buf][w * 1024];
        ushort* Bsw = &Bs[buf][w * 1024];
        gload16(Ag + kt, Asw);
        gload16(Ag + 16 * K + kt, Asw + 512);
        gload16(Bg + kt, Bsw);
        gload16(Bg + 16 * K + kt, Bsw + 512);
    };
    auto COMPUTE = [&](int buf) {
        bf16x8 af[4], bfr[4];
#pragma unroll
        for (int fm = 0; fm < 4; ++fm)
            af[fm] = *(const bf16x8*)&As[buf][arow + fm * 512 + koff];
#pragma unroll
        for (int fn = 0; fn < 4; ++fn)
            bfr[fn] = *(const bf16x8*)&Bs[buf][brow + fn * 512 + koff];
#pragma unroll
        for (int fm = 0; fm < 4; ++fm)
#pragma unroll
            for (int fn = 0; fn < 4; ++fn)
                acc[fm][fn] = __builtin_amdgcn_mfma_f32_16x16x32_bf16(
                    af[fm], bfr[fn], acc[fm][fn], 0, 0, 0);
    };

    STAGE(0, 0);
    asm volatile("s_waitcnt vmcnt(0)" ::: "memory");
    __builtin_amdgcn_s_barrier();
    int cur = 0;
    for (int kt = 32; kt < K; kt += 32) {
        STAGE(cur ^ 1, kt);
        COMPUTE(cur);
        asm volatile("s_waitcnt vmcnt(0)" ::: "memory");
        __builtin_amdgcn_s_barrier();
        cur ^= 1;
    }
    COMPUTE(cur);

    const int crow = (l >> 4) * 4;
    const int ccol = l & 15;
#pragma unroll
    for (int fm = 0; fm < 4; ++fm)
#pragma unroll
        for (int fn = 0; fn < 4; ++fn)
#pragma unroll
            for (int r = 0; r < 4; ++r) {
                size_t row = row0 + wr + fm * 16 + crow + r;
                size_t col = col0 + wc + fn * 16 + ccol;
                C[row * N + col] = acc[fm][fn][r];
            }
}

// ---------------------------------------------------------------------------
// Flash attention: swapped QK^T, 32x32x16 MFMA, fixed-max exp2 softmax.
// r15 base + T5 setprio(1) around both MFMA clusters (m191: +4-7% attn when
// independent wave-groups co-resident; here 8 blocks/CU at staggered phases).
// ---------------------------------------------------------------------------
__global__ __launch_bounds__(256, 4)
void attn_bf16_v2(const ushort* __restrict__ Q, const ushort* __restrict__ K,
                  const ushort* __restrict__ V, ushort* __restrict__ O)
{
    __shared__ uint shm[4352];        // Ksu [0,2176) ; Vtu [2176,4352)
    uint* Ksu = shm;                  // K tile u32 pairs, row stride 34
    uint* Vtu = shm + 2176;           // V^T tile: row d, cols key-pairs

    const int tid = threadIdx.x;
    const int w = tid >> 6, l = tid & 63;
    const int lo = l & 31, hi = l >> 5;
    const int bid = blockIdx.x;
    const int qt = bid >> 7;
    const int hb = bid & 127;
    const int h = hb >> 3, b = hb & 7;
    const int colh = h * 64;

    const size_t qrow = (size_t)(b * 1024 + qt * 128 + w * 32 + lo);
    bf16x8 qb[4];
#pragma unroll
    for (int kc = 0; kc < 4; ++kc)
        qb[kc] = *(const bf16x8*)&Q[qrow * 1024 + colh + kc * 16 + hi * 8];

    f32x16 acc[2];
#pragma unroll
    for (int i = 0; i < 2; ++i) acc[i] = (f32x16)0.f;
    float lsum = 0.f;

    const size_t kvbase = (size_t)b * 1024 * 1024 + colh;  // + key*1024 + d

    const int skey = tid >> 3, sc = tid & 7;  // K staging
    const int kp = tid & 31, vg = tid >> 5;   // V staging

    for (int kt = 0; kt < 16; ++kt) {
        __syncthreads();
#pragma unroll
        for (int u = 0; u < 2; ++u) {
            int key = skey + u * 32;
            uint4 kv = *(const uint4*)&K[kvbase + (size_t)(kt * 64 + key) * 1024 + sc * 8];
            *(uint2*)&Ksu[key * 34 + sc * 4] = make_uint2(kv.x, kv.y);
            *(uint2*)&Ksu[key * 34 + sc * 4 + 2] = make_uint2(kv.z, kv.w);
        }
        {
            uint4 va = *(const uint4*)&V[kvbase + (size_t)(kt * 64 + 2 * kp) * 1024 + vg * 8];
            uint4 vb = *(const uint4*)&V[kvbase + (size_t)(kt * 64 + 2 * kp + 1) * 1024 + vg * 8];
            const ushort* pa = (const ushort*)&va;
            const ushort* pb = (const ushort*)&vb;
#pragma unroll
            for (int e = 0; e < 8; ++e)
                Vtu[(vg * 8 + e) * 34 + kp] = (uint)pa[e] | ((uint)pb[e] << 16);
        }
        __syncthreads();

        uint pw[16];
#pragma unroll
        for (int mt = 0; mt < 2; ++mt) {
            f32x16 s = (f32x16)0.f;
            const int rbase = (mt * 32 + lo) * 34 + hi * 4;
            __builtin_amdgcn_s_setprio(1);
#pragma unroll
            for (int kc = 0; kc < 4; ++kc) {
                union { uint2 d[2]; bf16x8 v; } ak;
                ak.d[0] = *(const uint2*)&Ksu[rbase + kc * 8];
                ak.d[1] = *(const uint2*)&Ksu[rbase + kc * 8 + 2];
                s = __builtin_amdgcn_mfma_f32_32x32x16_bf16(ak.v, qb[kc], s, 0, 0, 0);
            }
            __builtin_amdgcn_s_setprio(0);
            float p[16];
#pragma unroll
            for (int r = 0; r < 16; ++r) {
                p[r] = exp2f(s[r]);
                lsum += p[r];
            }
#pragma unroll
            for (int rp = 0; rp < 8; ++rp)
                pw[mt * 8 + rp] = cvt_pk_bf16(p[2 * rp], p[2 * rp + 1]);
        }

        bf16x8 pf[4];
#pragma unroll
        for (int mt = 0; mt < 2; ++mt) {
            uint* W = &pw[mt * 8];
            uint e0 = (uint)__shfl_xor((int)(hi ? W[0] : W[2]), 32);
            uint e1 = (uint)__shfl_xor((int)(hi ? W[1] : W[3]), 32);
            uint e2 = (uint)__shfl_xor((int)(hi ? W[4] : W[6]), 32);
            uint e3 = (uint)__shfl_xor((int)(hi ? W[5] : W[7]), 32);
            union { uint u[4]; bf16x8 v; } f0, f1;
            if (hi == 0) {
                f0.u[0] = W[0]; f0.u[1] = W[1]; f0.u[2] = e0; f0.u[3] = e1;
                f1.u[0] = W[4]; f1.u[1] = W[5]; f1.u[2] = e2; f1.u[3] = e3;
            } else {
                f0.u[0] = e0; f0.u[1] = e1; f0.u[2] = W[2]; f0.u[3] = W[3];
                f1.u[0] = e2; f1.u[1] = e3; f1.u[2] = W[6]; f1.u[3] = W[7];
            }
            pf[mt * 2 + 0] = f0.v;
            pf[mt * 2 + 1] = f1.v;
        }

        __builtin_amdgcn_s_setprio(1);
#pragma unroll
        for (int dmt = 0; dmt < 2; ++dmt) {
            const int rbase = (dmt * 32 + lo) * 34 + hi * 4;
#pragma unroll
            for (int kcg = 0; kcg < 4; ++kcg) {
                union { uint2 d[2]; bf16x8 v; } vk;
                vk.d[0] = *(const uint2*)&Vtu[rbase + kcg * 8];
                vk.d[1] = *(const uint2*)&Vtu[rbase + kcg * 8 + 2];
                acc[dmt] = __builtin_amdgcn_mfma_f32_32x32x16_bf16(vk.v, pf[kcg], acc[dmt], 0, 0, 0);
            }
        }
        __builtin_amdgcn_s_setprio(0);
    }

    float tot = lsum + __shfl_xor(lsum, 32);
    float inv = 1.0f / tot;

    // epilogue O^T -> O via LDS union (Ksu/Vtu space is dead after the loop)
    __syncthreads();                   // all waves done reading K/V tiles
    uint* Osw = shm + w * 1056;        // 32 rows x 33 u32 per wave
#pragma unroll
    for (int dmt = 0; dmt < 2; ++dmt)
#pragma unroll
        for (int rp = 0; rp < 8; ++rp) {
            float a0 = acc[dmt][2 * rp] * inv;
            float a1 = acc[dmt][2 * rp + 1] * inv;
            Osw[lo * 33 + dmt * 16 + (rp & 1) + 4 * (rp >> 1) + 2 * hi] =
                cvt_pk_bf16(a0, a1);
        }
    __builtin_amdgcn_s_waitcnt(0);     // lgkm drain before same-wave readback
#pragma unroll
    for (int u = 0; u < 4; ++u) {
        int slot = l + u * 64;
        int qr = slot >> 3, c = slot & 7;
        float4 val = *(const float4*)&Osw[qr * 33 + c * 4];
        *(float4*)&O[(size_t)(b * 1024 + qt * 128 + w * 32 + qr) * 1024 + colh + c * 8] = val;
    }
}

// ---------------------------------------------------------------------------
extern "C" void kernel_launch(void* const* d_in, const int* in_sizes, int n_in,
                              void* d_out, int out_size, void* d_ws, size_t ws_size,
                              hipStream_t stream)
{
    const float* xq  = (const float*)d_in[0];
    const float* xkv = (const float*)d_in[1];
    const float* wq  = (const float*)d_in[2];
    const float* wk  = (const float*)d_in[3];
    const float* wv  = (const float*)d_in[4];
    const float* wo  = (const float*)d_in[5];
    float* out = (float*)d_out;

    const int M = 8192, N = 1024, Kd = 1024;
    ushort* Aq  = (ushort*)d_ws;            // 8M bf16
    ushort* Akv = Aq  + 8388608;
    ushort* WqT = Akv + 8388608;            // 1M each; WqT/WkT/WvT contiguous
    ushort* WkT = WqT + 1048576;
    ushort* WvT = WkT + 1048576;
    ushort* WoT = WvT + 1048576;
    ushort* Qb  = WoT + 1048576;            // 8M each; Qb/Kb/Vb contiguous
    ushort* Kb  = Qb  + 8388608;
    ushort* Vb  = Kb  + 8388608;
    ushort* Ob  = Vb  + 8388608;
    float2* Tbl = (float2*)(Ob + 8388608);  // 32768 float2 = 256 KB

    prep<<<12416, 256, 0, stream>>>(xq, Aq, xkv, Akv, wq, WqT, wk, WkT,
                                    wv, WvT, wo, WoT, Tbl);

    gemm_qkv<<<dim3(64, 24), 256, 0, stream>>>(Aq, Akv, WqT, Qb, Tbl);

    attn_bf16_v2<<<1024, 256, 0, stream>>>(Qb, Kb, Vb, Ob);

    gemm_out<<<dim3(64, 8), 256, 0, stream>>>(Ob, WoT, out, M, N, Kd);
}